// Round 1
// baseline (288.132 us; speedup 1.0000x reference)
//
#include <hip/hip_runtime.h>
#include <stdint.h>

// Cost volume = 48-wide band of Gram matrix L^T R per (b,h), K = c = 128.
// bf16 MFMA (32x32x16), memory-bound target ~47us (298 MB @ 6.3 TB/s).

typedef __bf16 bf16x8 __attribute__((ext_vector_type(8)));
typedef short short8v __attribute__((ext_vector_type(8)));
typedef float floatx16 __attribute__((ext_vector_type(16)));

constexpr int W = 320, H = 96, C = 128, NB = 8, MAXD = 48;
constexpr int HW = H * W;      // 30720
constexpr int KC = 32;         // c-chunk staged per iteration

__device__ __forceinline__ uint32_t pack_bf16x2(float a, float b) {
    // round-to-nearest-even f32 -> bf16, packed (b in high half)
    uint32_t ua = __float_as_uint(a), ub = __float_as_uint(b);
    uint32_t lo = (ua + 0x7fffu + ((ua >> 16) & 1u)) >> 16;
    uint32_t hi = (ub + 0x7fffu + ((ub >> 16) & 1u)) & 0xffff0000u;
    return hi | lo;
}

__global__ __launch_bounds__(640, 5) void cost_volume_kernel(
    const float* __restrict__ Lg, const float* __restrict__ Rg,
    float* __restrict__ out)
{
    // LDS: staging (bf16 [KC][320] x2 = 40960 B) reused later as the
    // store-transpose scratch (10 waves * 48*33 f32 = 63360 B).
    __shared__ uint32_t lds[15840];
    ushort* sL = reinterpret_cast<ushort*>(lds);
    ushort* sR = sL + KC * W;

    const int t    = threadIdx.x;
    const int lane = t & 63;
    const int p    = t >> 6;        // wave id = x-tile id (10 tiles of 32)
    const int n    = lane & 31;
    const int half = lane >> 5;     // 0/1

    const int b = blockIdx.x / H;
    const int h = blockIdx.x % H;
    const int baseLR = b * (C * HW) + h * W;

    floatx16 acc0 = 0.f, acc1 = 0.f, acc2 = 0.f;  // q = p, p-1, p-2

    for (int c0 = 0; c0 < C; c0 += KC) {
        // ---- stage KC c-rows of L and R as bf16 [c][x] ----
#pragma unroll
        for (int j = 0; j < 4; ++j) {
            int idx = j * 640 + t;            // 0..2559
            int row = idx / 80;               // c-local 0..31
            int col = (idx % 80) * 4;         // x 0..316 step 4
            int g = baseLR + (c0 + row) * HW + col;
            float4 vl = *reinterpret_cast<const float4*>(Lg + g);
            float4 vr = *reinterpret_cast<const float4*>(Rg + g);
            uint32_t* dl = reinterpret_cast<uint32_t*>(sL + row * W + col);
            dl[0] = pack_bf16x2(vl.x, vl.y);
            dl[1] = pack_bf16x2(vl.z, vl.w);
            uint32_t* dr = reinterpret_cast<uint32_t*>(sR + row * W + col);
            dr[0] = pack_bf16x2(vr.x, vr.y);
            dr[1] = pack_bf16x2(vr.z, vr.w);
        }
        __syncthreads();

        // ---- MFMA: 2 K=16 slices per chunk ----
#pragma unroll
        for (int ks = 0; ks < 2; ++ks) {
            const int kb = ks * 16 + half * 8;   // lane's c-local k base
            // A fragment: L[kb+j][32p+n]
            const ushort* pa = sL + kb * W + p * 32 + n;
            short8v av;
#pragma unroll
            for (int j = 0; j < 8; ++j) av[j] = (short)pa[j * W];
            bf16x8 af = __builtin_bit_cast(bf16x8, av);

            {   // q = p
                const ushort* pb = sR + kb * W + p * 32 + n;
                short8v bv;
#pragma unroll
                for (int j = 0; j < 8; ++j) bv[j] = (short)pb[j * W];
                acc0 = __builtin_amdgcn_mfma_f32_32x32x16_bf16(
                    af, __builtin_bit_cast(bf16x8, bv), acc0, 0, 0, 0);
            }
            if (p >= 1) {   // q = p-1
                const ushort* pb = sR + kb * W + (p - 1) * 32 + n;
                short8v bv;
#pragma unroll
                for (int j = 0; j < 8; ++j) bv[j] = (short)pb[j * W];
                acc1 = __builtin_amdgcn_mfma_f32_32x32x16_bf16(
                    af, __builtin_bit_cast(bf16x8, bv), acc1, 0, 0, 0);
            }
            if (p >= 2) {   // q = p-2
                const ushort* pb = sR + kb * W + (p - 2) * 32 + n;
                short8v bv;
#pragma unroll
                for (int j = 0; j < 8; ++j) bv[j] = (short)pb[j * W];
                acc2 = __builtin_amdgcn_mfma_f32_32x32x16_bf16(
                    af, __builtin_bit_cast(bf16x8, bv), acc2, 0, 0, 0);
            }
        }
        __syncthreads();
    }

    // ---- epilogue: band -> per-wave LDS transpose -> coalesced stores ----
    // D layout (measured): m = (r&3) + 8*(r>>2) + 4*(lane>>5), n = lane&31
    float* sS = reinterpret_cast<float*>(lds) + p * (MAXD * 33);

    if (p < 2) {  // only x<64 has an i>x zero triangle
        for (int e = lane; e < MAXD * 33; e += 64) sS[e] = 0.f;
    }

#define FILL_TILE(DP, ACC)                                                  \
    if (p >= (DP)) {                                                        \
        _Pragma("unroll")                                                   \
        for (int r = 0; r < 16; ++r) {                                      \
            int m = (r & 3) + 8 * (r >> 2) + 4 * half;                      \
            int i = 32 * (DP) + m - n;                                      \
            if (i >= 0 && i < MAXD)                                         \
                sS[i * 33 + m] = ACC[r] * (1.f / 128.f);                    \
        }                                                                   \
    }
    FILL_TILE(0, acc0)
    FILL_TILE(1, acc1)
    FILL_TILE(2, acc2)
#undef FILL_TILE

    const int ob = b * (MAXD * HW) + h * W + p * 32;
#pragma unroll
    for (int e = 0; e < 24; ++e) {
        int idx = e * 64 + lane;
        int i = idx >> 5;        // disparity 0..47
        int m = idx & 31;        // x-local
        out[ob + i * HW + m] = sS[i * 33 + m];
    }
}

extern "C" void kernel_launch(void* const* d_in, const int* in_sizes, int n_in,
                              void* d_out, int out_size, void* d_ws, size_t ws_size,
                              hipStream_t stream) {
    const float* L = (const float*)d_in[0];
    const float* R = (const float*)d_in[1];
    float* out = (float*)d_out;
    cost_volume_kernel<<<dim3(NB * H), dim3(640), 0, stream>>>(L, R, out);
}